// Round 10
// baseline (30687.878 us; speedup 1.0000x reference)
//
#include <hip/hip_runtime.h>

// ---------------------------------------------------------------------------
// StackedBLSTMEmbedding: B=32, T=2000, D=80, H=256/dir, HD=512, O=512
// Round 10: r8 + OOB fix. r9 crash root-cause: layer-2 f32 xg needed 262MB
//   but tier check guaranteed 131MB -> OOB write. Fix: window layer 2 as
//   2x500 steps reusing the same 131MB region (state carry already existed).
//   VC 26->24 for VGPR headroom (spill cliff, r5 lesson).
//   lstm2: 512 thr/block (2 waves/SIMD), thread owns 2 full gate rows,
//   Whh 24 chunks VGPR + 8 chunks LDS, precise expf/tanhf, f32 xg.
// ---------------------------------------------------------------------------

typedef _Float16 h2_t __attribute__((ext_vector_type(2)));

constexpr int VC = 24;            // Whh k8-chunks in VGPRs (48 uint4 = 192 regs)
constexpr int LCH = 32 - VC;      // 8 chunks in LDS (128 KB)

__device__ __forceinline__ float dot2acc(unsigned int w, unsigned int h, float acc) {
  h2_t wv = __builtin_bit_cast(h2_t, w);
  h2_t hv = __builtin_bit_cast(h2_t, h);
#if __has_builtin(__builtin_amdgcn_fdot2)
  return __builtin_amdgcn_fdot2(wv, hv, acc, false);
#else
  return acc + (float)wv[0] * (float)hv[0] + (float)wv[1] * (float)hv[1];
#endif
}

__device__ __forceinline__ float dot8(uint4 w, uint4 h, float acc) {
  acc = dot2acc(w.x, h.x, acc);
  acc = dot2acc(w.y, h.y, acc);
  acc = dot2acc(w.z, h.z, acc);
  acc = dot2acc(w.w, h.w, acc);
  return acc;
}

__device__ __forceinline__ float sigf(float x) { return 1.f / (1.f + expf(-x)); }

// Pack fp32 W[1024][K] -> f16 uint4 Wp[k8][1024] (k8 = k/8).
__global__ __launch_bounds__(256) void pack_w(const float* __restrict__ W,
                                              uint4* __restrict__ Wp, int K) {
  const int idx = blockIdx.x * 256 + threadIdx.x;
  const int total = (K >> 3) << 10;
  if (idx >= total) return;
  const int g = idx & 1023;
  const int k8 = idx >> 10;
  const float* src = W + (size_t)g * K + k8 * 8;
  h2_t p0, p1, p2, p3;
  p0[0] = (_Float16)src[0]; p0[1] = (_Float16)src[1];
  p1[0] = (_Float16)src[2]; p1[1] = (_Float16)src[3];
  p2[0] = (_Float16)src[4]; p2[1] = (_Float16)src[5];
  p3[0] = (_Float16)src[6]; p3[1] = (_Float16)src[7];
  uint4 o;
  o.x = __builtin_bit_cast(unsigned int, p0);
  o.y = __builtin_bit_cast(unsigned int, p1);
  o.z = __builtin_bit_cast(unsigned int, p2);
  o.w = __builtin_bit_cast(unsigned int, p3);
  Wp[(size_t)k8 * 1024 + g] = o;
}

__global__ __launch_bounds__(256) void pack_flat(const float* __restrict__ src,
                                                 _Float16* __restrict__ dst, int n) {
  const int i = blockIdx.x * 256 + threadIdx.x;
  if (i < n) dst[i] = (_Float16)src[i];
}

__global__ __launch_bounds__(256) void zero16(uint4* __restrict__ p, int n16) {
  const int i = blockIdx.x * 256 + threadIdx.x;
  if (i < n16) { uint4 z; z.x = z.y = z.z = z.w = 0u; p[i] = z; }
}

// C[M][N] = A'[M][K] @ B[N][K]^T + bias.  M%128==0, N%64==0, K%16==0.
// Window remap (Twin>0): row m -> b=m/Twin, ti=t0+m%Twin; REV: ti=len_b-1-ti
// (clamped); A-row = b*Tfull+ti. Twin==0: identity.
template <typename AT, typename CT>
__global__ __launch_bounds__(256) void gemm_any(
    const AT* __restrict__ A, const float* __restrict__ B,
    const float* __restrict__ bias, CT* __restrict__ C,
    int M, int N, int K, int Twin, int Tfull, int t0, int REV,
    const int* __restrict__ x_len, int lensh) {
  __shared__ float As[16][128];
  __shared__ float Bs[16][64];
  const int tid = threadIdx.x;
  const int m0 = blockIdx.y * 128, n0 = blockIdx.x * 64;
  const int ra = tid >> 1;
  const int ca = (tid & 1) * 8;
  const int rb = tid >> 2;
  const int cb = (tid & 3) * 4;
  const int ty = tid >> 4;
  const int tx = tid & 15;
  const int am = m0 + ra;
  int arow = am;
  if (Twin > 0) {
    const int bb = am / Twin;
    int ti = t0 + (am - bb * Twin);
    if (REV) {
      const int L = x_len[bb] >> lensh;
      ti = L - 1 - ti;
      ti = ti < 0 ? 0 : ti;
    }
    arow = bb * Tfull + ti;
  }
  float acc[8][4] = {};
  for (int k0 = 0; k0 < K; k0 += 16) {
    float a8[8];
    if constexpr (sizeof(AT) == 2) {
      const uint4 av = *reinterpret_cast<const uint4*>(&A[(size_t)arow * K + k0 + ca]);
      h2_t p0 = __builtin_bit_cast(h2_t, av.x);
      h2_t p1 = __builtin_bit_cast(h2_t, av.y);
      h2_t p2 = __builtin_bit_cast(h2_t, av.z);
      h2_t p3 = __builtin_bit_cast(h2_t, av.w);
      a8[0] = (float)p0[0]; a8[1] = (float)p0[1];
      a8[2] = (float)p1[0]; a8[3] = (float)p1[1];
      a8[4] = (float)p2[0]; a8[5] = (float)p2[1];
      a8[6] = (float)p3[0]; a8[7] = (float)p3[1];
    } else {
      const float4 a0 = *reinterpret_cast<const float4*>(&A[(size_t)arow * K + k0 + ca]);
      const float4 a1 = *reinterpret_cast<const float4*>(&A[(size_t)arow * K + k0 + ca + 4]);
      a8[0] = a0.x; a8[1] = a0.y; a8[2] = a0.z; a8[3] = a0.w;
      a8[4] = a1.x; a8[5] = a1.y; a8[6] = a1.z; a8[7] = a1.w;
    }
    const float4 b0 = *reinterpret_cast<const float4*>(&B[(size_t)(n0 + rb) * K + k0 + cb]);
    __syncthreads();
#pragma unroll
    for (int q = 0; q < 8; ++q) As[ca + q][ra] = a8[q];
    Bs[cb + 0][rb] = b0.x; Bs[cb + 1][rb] = b0.y;
    Bs[cb + 2][rb] = b0.z; Bs[cb + 3][rb] = b0.w;
    __syncthreads();
#pragma unroll
    for (int kk = 0; kk < 16; ++kk) {
      const float4 av0 = *reinterpret_cast<const float4*>(&As[kk][ty * 8]);
      const float4 av1 = *reinterpret_cast<const float4*>(&As[kk][ty * 8 + 4]);
      const float4 bv  = *reinterpret_cast<const float4*>(&Bs[kk][tx * 4]);
      const float a[8] = {av0.x, av0.y, av0.z, av0.w, av1.x, av1.y, av1.z, av1.w};
      const float bb4[4] = {bv.x, bv.y, bv.z, bv.w};
#pragma unroll
      for (int i = 0; i < 8; ++i)
#pragma unroll
        for (int j = 0; j < 4; ++j) acc[i][j] += a[i] * bb4[j];
    }
  }
  const float4 bias4 = *reinterpret_cast<const float4*>(&bias[n0 + tx * 4]);
  const float bb4[4] = {bias4.x, bias4.y, bias4.z, bias4.w};
#pragma unroll
  for (int i = 0; i < 8; ++i) {
    const size_t cidx = (size_t)(m0 + ty * 8 + i) * N + n0 + tx * 4;
    if constexpr (sizeof(CT) == 2) {
      h2_t lo, hi;
      lo[0] = (_Float16)(acc[i][0] + bb4[0]); lo[1] = (_Float16)(acc[i][1] + bb4[1]);
      hi[0] = (_Float16)(acc[i][2] + bb4[2]); hi[1] = (_Float16)(acc[i][3] + bb4[3]);
      uint2 st;
      st.x = __builtin_bit_cast(unsigned int, lo);
      st.y = __builtin_bit_cast(unsigned int, hi);
      *reinterpret_cast<uint2*>(&C[cidx]) = st;
    } else {
      float4 o;
      o.x = acc[i][0] + bb4[0]; o.y = acc[i][1] + bb4[1];
      o.z = acc[i][2] + bb4[2]; o.w = acc[i][3] + bb4[3];
      *reinterpret_cast<float4*>(&C[cidx]) = o;
    }
  }
}

// ---------------------------------------------------------------------------
// On-chip recurrence, 512 threads per (b,dir). Thread (u = t&255, p = t>>8)
// owns 2 complete gate rows: r0 = p*512+u (gate 2p), r1 = p*512+256+u (2p+1).
// Whh: chunks 0..VC-1 in VGPRs, VC..31 in LDS. h f16 in LDS (broadcast reads).
// Gate pair {ag,ao} handed from p=1 to p=0 via 8B LDS; p=0 holds c/h state.
// xg precomputed f32 (bias included; bwd time-reversed). 2 barriers/step.
// ---------------------------------------------------------------------------
template <int POOL>
__global__ __launch_bounds__(512, 2) void lstm2(
    const float* __restrict__ xgF, const float* __restrict__ xgB,
    const uint4* __restrict__ whhF, const uint4* __restrict__ whhB,
    _Float16* __restrict__ outp, const int* __restrict__ x_len,
    float* __restrict__ stC, _Float16* __restrict__ stH, float* __restrict__ stP,
    int lenshift, int T, int Twin, int s0) {
  const int b = blockIdx.x;
  const int dir = blockIdx.y;
  const int t_ = threadIdx.x;
  const int u = t_ & 255;
  const int p = t_ >> 8;
  const int len = x_len[b] >> lenshift;
  if (s0 >= len) return;                  // block-uniform
  const int ns = min(Twin, len - s0);
  const int col0 = dir ? 256 : 0;
  const int Tp = T >> 1;
  const int sidx = (b * 2 + dir) * 256 + u;
  const uint4* whh = dir ? whhB : whhF;
  const float* xg = dir ? xgB : xgF;
  const int r0 = p * 512 + u;
  const int r1 = p * 512 + 256 + u;

  // VGPR-resident weight chunks
  uint4 w0[VC], w1[VC];
#pragma unroll
  for (int k = 0; k < VC; ++k) {
    w0[k] = whh[(k << 10) + r0];
    w1[k] = whh[(k << 10) + r1];
  }
  // LDS-resident weight chunks
  __shared__ uint4 wlds[LCH][1024];                // 128 KB
  __shared__ __align__(16) _Float16 hb[2][256];    // 1 KB
  __shared__ float2 gl[256];                       // 2 KB
#pragma unroll
  for (int kc = 0; kc < LCH; ++kc) {
    wlds[kc][r0] = whh[((VC + kc) << 10) + r0];
    wlds[kc][r1] = whh[((VC + kc) << 10) + r1];
  }
  if (t_ < 256) hb[0][t_] = stH[(b * 2 + dir) * 256 + t_];
  float c = 0.f, hpend = 0.f;
  if (p == 0) { c = stC[sidx]; hpend = stP[sidx]; }
  __syncthreads();

  int par = 0;
  const float* xq = xg + (size_t)b * Twin * 1024 + p * 512 + u;
  float xa = xq[0];
  float xb2 = xq[256];
  for (int j = 0; j < ns; ++j) {
    const int s = s0 + j;
    const int t = dir ? (len - 1 - s) : s;
    float a0 = xa, a1 = xb2;
    const uint4* hp = reinterpret_cast<const uint4*>(hb[par]);
#pragma unroll
    for (int k = 0; k < VC; ++k) {
      const uint4 hv = hp[k];
      a0 = dot8(w0[k], hv, a0);
      a1 = dot8(w1[k], hv, a1);
    }
#pragma unroll
    for (int kc = 0; kc < LCH; ++kc) {
      const uint4 hv = hp[VC + kc];
      a0 = dot8(wlds[kc][r0], hv, a0);
      a1 = dot8(wlds[kc][r1], hv, a1);
    }
    if (j + 1 < ns) {   // prefetch next step's xg (independent of h)
      xa = xq[(size_t)(j + 1) * 1024];
      xb2 = xq[(size_t)(j + 1) * 1024 + 256];
    }
    if (p) { gl[u].x = a0; gl[u].y = a1; }
    __syncthreads();  // B1: gate pair {ag,ao} visible
    if (!p) {
      const float2 g2 = gl[u];
      const float gi = sigf(a0);
      const float gf = sigf(a1);
      const float gc = tanhf(g2.x);
      const float go = sigf(g2.y);
      c = gf * c + gi * gc;
      const float h = go * tanhf(c);
      hb[par ^ 1][u] = (_Float16)h;
      if (POOL) {
        if (dir == 0) {
          if (t & 1) outp[((size_t)b * Tp + (t >> 1)) * 512 + col0 + u] = (_Float16)fmaxf(hpend, h);
          else hpend = h;
        } else {
          if (t & 1) hpend = h;
          else outp[((size_t)b * Tp + (t >> 1)) * 512 + col0 + u] = (_Float16)fmaxf(h, hpend);
        }
      } else {
        outp[((size_t)b * T + t) * 512 + col0 + u] = (_Float16)h;
      }
    }
    __syncthreads();  // B2: h complete, gl consumed
    par ^= 1;
  }
  if (p == 0) {
    stH[sidx] = hb[par][u];
    stC[sidx] = c;
    stP[sidx] = hpend;
    if (POOL && dir == 0 && (len & 1) && (len - s0) <= Twin) {
      outp[((size_t)b * Tp + ((len - 1) >> 1)) * 512 + col0 + u] = (_Float16)fmaxf(hpend, 0.f);
    }
  }
}

// r4-style streaming recurrence (fallback for small workspace), ONFLY.
template <int POOL>
__global__ __launch_bounds__(256) void lstm_stream(
    const uint4* __restrict__ xh, int kx8,
    const uint4* __restrict__ wih_f, const uint4* __restrict__ wih_b,
    const float* __restrict__ bias_f, const float* __restrict__ bias_b,
    const uint4* __restrict__ whh_f, const uint4* __restrict__ whh_b,
    _Float16* __restrict__ outp, const int* __restrict__ x_len,
    int lenshift, int T) {
  const int b = blockIdx.x;
  const int dir = blockIdx.y;
  const int u = threadIdx.x;
  const int len = x_len[b] >> lenshift;
  const uint4* wih = dir ? wih_b : wih_f;
  const float* bias = dir ? bias_b : bias_f;
  const uint4* whh0 = (dir ? whh_b : whh_f) + u;
  const int col0 = dir ? 256 : 0;
  const float bi = bias[u], bff = bias[u + 256], bg = bias[u + 512], bo = bias[u + 768];
  __shared__ __align__(16) _Float16 hbuf[2][256];
  hbuf[0][u] = (_Float16)0.f;
  float c = 0.f, hpend = 0.f;
  __syncthreads();
  int cur = 0;
  const int Tp = T >> 1;
  for (int s = 0; s < len; ++s) {
    const int t = dir ? (len - 1 - s) : s;
    float ai = bi, af = bff, ag = bg, ao = bo;
    const uint4* xr = xh + ((size_t)b * T + t) * kx8;
    const uint4* wir = wih + u;
    for (int k8 = 0; k8 < kx8; ++k8) {
      const uint4 xv = xr[k8];
      ai = dot8(wir[0],   xv, ai);
      af = dot8(wir[256], xv, af);
      ag = dot8(wir[512], xv, ag);
      ao = dot8(wir[768], xv, ao);
      wir += 1024;
    }
    const uint4* hp = reinterpret_cast<const uint4*>(hbuf[cur]);
#pragma unroll 4
    for (int k8 = 0; k8 < 32; ++k8) {
      const uint4 hv = hp[k8];
      const uint4* wr = whh0 + (k8 << 10);
      ai = dot8(wr[0],   hv, ai);
      af = dot8(wr[256], hv, af);
      ag = dot8(wr[512], hv, ag);
      ao = dot8(wr[768], hv, ao);
    }
    const float gi = sigf(ai);
    const float gf = sigf(af);
    const float gg = tanhf(ag);
    const float go = sigf(ao);
    c = gf * c + gi * gg;
    const float h = go * tanhf(c);
    if (POOL) {
      if (dir == 0) {
        if (t & 1) outp[((size_t)b * Tp + (t >> 1)) * 512 + col0 + u] = (_Float16)fmaxf(hpend, h);
        else hpend = h;
      } else {
        if (t & 1) hpend = h;
        else outp[((size_t)b * Tp + (t >> 1)) * 512 + col0 + u] = (_Float16)fmaxf(h, hpend);
      }
    } else {
      outp[((size_t)b * T + t) * 512 + col0 + u] = (_Float16)h;
    }
    hbuf[cur ^ 1][u] = (_Float16)h;
    cur ^= 1;
    __syncthreads();
  }
  if (POOL && dir == 0 && (len & 1)) {
    outp[((size_t)b * Tp + ((len - 1) >> 1)) * 512 + col0 + u] = (_Float16)fmaxf(hpend, 0.f);
  }
}

__global__ void lens_k(const int* __restrict__ x_len, float* __restrict__ dst) {
  const int b = threadIdx.x;
  if (b < 32) dst[b] = (float)(x_len[b] >> 1);
}

extern "C" void kernel_launch(void* const* d_in, const int* in_sizes, int n_in,
                              void* d_out, int out_size, void* d_ws, size_t ws_size,
                              hipStream_t stream) {
  (void)in_sizes; (void)n_in; (void)out_size;
  const float* x     = (const float*)d_in[0];
  const int*   x_len = (const int*)d_in[1];
  const float* Wih1f = (const float*)d_in[2];
  const float* Whh1f = (const float*)d_in[3];
  const float* b1f   = (const float*)d_in[4];
  const float* Wih1b = (const float*)d_in[5];
  const float* Whh1b = (const float*)d_in[6];
  const float* b1b   = (const float*)d_in[7];
  const float* Wih2f = (const float*)d_in[8];
  const float* Whh2f = (const float*)d_in[9];
  const float* b2f   = (const float*)d_in[10];
  const float* Wih2b = (const float*)d_in[11];
  const float* Whh2b = (const float*)d_in[12];
  const float* b2b   = (const float*)d_in[13];
  const float* Wlin  = (const float*)d_in[14];
  const float* blin  = (const float*)d_in[15];
  float* outF = (float*)d_out;

  char* w = (char*)d_ws;
  size_t off = 0;
  auto alloc = [&](size_t bytes) -> void* {
    void* p = w + off;
    off += (bytes + 255) & ~(size_t)255;
    return p;
  };
  uint4* wp_hh1f = (uint4*)alloc(524288);
  uint4* wp_hh1b = (uint4*)alloc(524288);
  uint4* wp_hh2f = (uint4*)alloc(524288);
  uint4* wp_hh2b = (uint4*)alloc(524288);
  uint4* wp_ih1f = (uint4*)alloc(163840);      // fallback only
  uint4* wp_ih1b = (uint4*)alloc(163840);
  uint4* wp_ih2f = (uint4*)alloc(1048576);
  uint4* wp_ih2b = (uint4*)alloc(1048576);
  _Float16* pooled = (_Float16*)alloc(32768000);  // [32][1000][512] f16
  _Float16* out2   = (_Float16*)alloc(32768000);  // [32][1000][512] f16 (contiguous)
  float*    stC1 = (float*)alloc(65536);          // states, contiguous block
  _Float16* stH1 = (_Float16*)alloc(32768);
  float*    stP1 = (float*)alloc(65536);
  float*    stC2 = (float*)alloc(65536);
  _Float16* stH2 = (_Float16*)alloc(32768);
  float*    stP2 = (float*)alloc(65536);
  const size_t var_off = off;
  float* varrF = (float*)(w + var_off);
  float* xgwF = varrF;                   // [32][500][1024] f32 = 65,536,000 B
  float* xgwB = varrF + 16384000;        // second 65,536,000 B (131MB total)
  _Float16* x_h = (_Float16*)(w + var_off);  // fallback: [32][2000][80] f16

  const int main_tier = (ws_size >= var_off + 131072000ULL) ? 1 : 0;

  // Whh packs (always)
  pack_w<<<128, 256, 0, stream>>>(Whh1f, wp_hh1f, 256);
  pack_w<<<128, 256, 0, stream>>>(Whh1b, wp_hh1b, 256);
  pack_w<<<128, 256, 0, stream>>>(Whh2f, wp_hh2f, 256);
  pack_w<<<128, 256, 0, stream>>>(Whh2b, wp_hh2b, 256);
  // zero pooled+out2 (contiguous) and all state buffers (contiguous)
  zero16<<<16000, 256, 0, stream>>>((uint4*)pooled, 4096000);
  zero16<<<80, 256, 0, stream>>>((uint4*)stC1, 20480);

  if (main_tier) {
    // ---- Layer 1: 4 windows of 500 steps, f32 xg ----
    for (int w4 = 0; w4 < 4; ++w4) {
      const int t0 = 500 * w4;
      gemm_any<float, float><<<dim3(16, 125), 256, 0, stream>>>(
          x, Wih1f, b1f, xgwF, 16000, 1024, 80, 500, 2000, t0, 0, x_len, 0);
      gemm_any<float, float><<<dim3(16, 125), 256, 0, stream>>>(
          x, Wih1b, b1b, xgwB, 16000, 1024, 80, 500, 2000, t0, 1, x_len, 0);
      lstm2<1><<<dim3(32, 2), 512, 0, stream>>>(
          xgwF, xgwB, wp_hh1f, wp_hh1b, pooled, x_len,
          stC1, stH1, stP1, 0, 2000, 500, t0);
    }
    // ---- Layer 2: 2 windows of 500 steps (same 131MB region) ----
    for (int w2 = 0; w2 < 2; ++w2) {
      const int t0 = 500 * w2;
      gemm_any<_Float16, float><<<dim3(16, 125), 256, 0, stream>>>(
          pooled, Wih2f, b2f, xgwF, 16000, 1024, 512, 500, 1000, t0, 0, x_len, 1);
      gemm_any<_Float16, float><<<dim3(16, 125), 256, 0, stream>>>(
          pooled, Wih2b, b2b, xgwB, 16000, 1024, 512, 500, 1000, t0, 1, x_len, 1);
      lstm2<0><<<dim3(32, 2), 512, 0, stream>>>(
          xgwF, xgwB, wp_hh2f, wp_hh2b, out2, x_len,
          stC2, stH2, stP2, 1, 1000, 500, t0);
    }
  } else {
    // ---- Fallback (r4-proven): ONFLY streaming both layers ----
    pack_w<<<40, 256, 0, stream>>>(Wih1f, wp_ih1f, 80);
    pack_w<<<40, 256, 0, stream>>>(Wih1b, wp_ih1b, 80);
    pack_w<<<256, 256, 0, stream>>>(Wih2f, wp_ih2f, 512);
    pack_w<<<256, 256, 0, stream>>>(Wih2b, wp_ih2b, 512);
    pack_flat<<<20000, 256, 0, stream>>>(x, x_h, 5120000);
    lstm_stream<1><<<dim3(32, 2), 256, 0, stream>>>(
        (const uint4*)x_h, 10, wp_ih1f, wp_ih1b, b1f, b1b,
        wp_hh1f, wp_hh1b, pooled, x_len, 0, 2000);
    lstm_stream<0><<<dim3(32, 2), 256, 0, stream>>>(
        (const uint4*)pooled, 64, wp_ih2f, wp_ih2b, b2f, b2b,
        wp_hh2f, wp_hh2b, out2, x_len, 1, 1000);
  }

  // ---- Final linear + lens ----
  gemm_any<_Float16, float><<<dim3(8, 250), 256, 0, stream>>>(
      out2, Wlin, blin, outF, 32000, 512, 512, 0, 0, 0, 0, nullptr, 0);
  lens_k<<<1, 32, 0, stream>>>(x_len, outF + (size_t)16384000);
}

// Round 11
// 30649.655 us; speedup vs baseline: 1.0012x; 1.0012x over previous
//
#include <hip/hip_runtime.h>

// ---------------------------------------------------------------------------
// StackedBLSTMEmbedding: B=32, T=2000, D=80, H=256/dir, HD=512, O=512
// Round 11: r10 with ONE change: __launch_bounds__(512) single-arg.
//   r10 lesson: (512,2) made the compiler cap VGPRs at 128 -> weight arrays
//   (192 regs) spilled/rematerialized -> 10us/step. A 512-thread block already
//   forces 2 waves/SIMD (VGPR cap 256); no second arg needed.
//   lstm2: thread owns 2 full gate rows, Whh 24 chunks VGPR + 8 chunks LDS,
//   precise expf/tanhf, f32 xg in 500-step windows both layers.
// ---------------------------------------------------------------------------

typedef _Float16 h2_t __attribute__((ext_vector_type(2)));

constexpr int VC = 24;            // Whh k8-chunks in VGPRs (48 uint4 = 192 regs)
constexpr int LCH = 32 - VC;      // 8 chunks in LDS (128 KB)

__device__ __forceinline__ float dot2acc(unsigned int w, unsigned int h, float acc) {
  h2_t wv = __builtin_bit_cast(h2_t, w);
  h2_t hv = __builtin_bit_cast(h2_t, h);
#if __has_builtin(__builtin_amdgcn_fdot2)
  return __builtin_amdgcn_fdot2(wv, hv, acc, false);
#else
  return acc + (float)wv[0] * (float)hv[0] + (float)wv[1] * (float)hv[1];
#endif
}

__device__ __forceinline__ float dot8(uint4 w, uint4 h, float acc) {
  acc = dot2acc(w.x, h.x, acc);
  acc = dot2acc(w.y, h.y, acc);
  acc = dot2acc(w.z, h.z, acc);
  acc = dot2acc(w.w, h.w, acc);
  return acc;
}

__device__ __forceinline__ float sigf(float x) { return 1.f / (1.f + expf(-x)); }

// Pack fp32 W[1024][K] -> f16 uint4 Wp[k8][1024] (k8 = k/8).
__global__ __launch_bounds__(256) void pack_w(const float* __restrict__ W,
                                              uint4* __restrict__ Wp, int K) {
  const int idx = blockIdx.x * 256 + threadIdx.x;
  const int total = (K >> 3) << 10;
  if (idx >= total) return;
  const int g = idx & 1023;
  const int k8 = idx >> 10;
  const float* src = W + (size_t)g * K + k8 * 8;
  h2_t p0, p1, p2, p3;
  p0[0] = (_Float16)src[0]; p0[1] = (_Float16)src[1];
  p1[0] = (_Float16)src[2]; p1[1] = (_Float16)src[3];
  p2[0] = (_Float16)src[4]; p2[1] = (_Float16)src[5];
  p3[0] = (_Float16)src[6]; p3[1] = (_Float16)src[7];
  uint4 o;
  o.x = __builtin_bit_cast(unsigned int, p0);
  o.y = __builtin_bit_cast(unsigned int, p1);
  o.z = __builtin_bit_cast(unsigned int, p2);
  o.w = __builtin_bit_cast(unsigned int, p3);
  Wp[(size_t)k8 * 1024 + g] = o;
}

__global__ __launch_bounds__(256) void pack_flat(const float* __restrict__ src,
                                                 _Float16* __restrict__ dst, int n) {
  const int i = blockIdx.x * 256 + threadIdx.x;
  if (i < n) dst[i] = (_Float16)src[i];
}

__global__ __launch_bounds__(256) void zero16(uint4* __restrict__ p, int n16) {
  const int i = blockIdx.x * 256 + threadIdx.x;
  if (i < n16) { uint4 z; z.x = z.y = z.z = z.w = 0u; p[i] = z; }
}

// C[M][N] = A'[M][K] @ B[N][K]^T + bias.  M%128==0, N%64==0, K%16==0.
// Window remap (Twin>0): row m -> b=m/Twin, ti=t0+m%Twin; REV: ti=len_b-1-ti
// (clamped); A-row = b*Tfull+ti. Twin==0: identity.
template <typename AT, typename CT>
__global__ __launch_bounds__(256) void gemm_any(
    const AT* __restrict__ A, const float* __restrict__ B,
    const float* __restrict__ bias, CT* __restrict__ C,
    int M, int N, int K, int Twin, int Tfull, int t0, int REV,
    const int* __restrict__ x_len, int lensh) {
  __shared__ float As[16][128];
  __shared__ float Bs[16][64];
  const int tid = threadIdx.x;
  const int m0 = blockIdx.y * 128, n0 = blockIdx.x * 64;
  const int ra = tid >> 1;
  const int ca = (tid & 1) * 8;
  const int rb = tid >> 2;
  const int cb = (tid & 3) * 4;
  const int ty = tid >> 4;
  const int tx = tid & 15;
  const int am = m0 + ra;
  int arow = am;
  if (Twin > 0) {
    const int bb = am / Twin;
    int ti = t0 + (am - bb * Twin);
    if (REV) {
      const int L = x_len[bb] >> lensh;
      ti = L - 1 - ti;
      ti = ti < 0 ? 0 : ti;
    }
    arow = bb * Tfull + ti;
  }
  float acc[8][4] = {};
  for (int k0 = 0; k0 < K; k0 += 16) {
    float a8[8];
    if constexpr (sizeof(AT) == 2) {
      const uint4 av = *reinterpret_cast<const uint4*>(&A[(size_t)arow * K + k0 + ca]);
      h2_t p0 = __builtin_bit_cast(h2_t, av.x);
      h2_t p1 = __builtin_bit_cast(h2_t, av.y);
      h2_t p2 = __builtin_bit_cast(h2_t, av.z);
      h2_t p3 = __builtin_bit_cast(h2_t, av.w);
      a8[0] = (float)p0[0]; a8[1] = (float)p0[1];
      a8[2] = (float)p1[0]; a8[3] = (float)p1[1];
      a8[4] = (float)p2[0]; a8[5] = (float)p2[1];
      a8[6] = (float)p3[0]; a8[7] = (float)p3[1];
    } else {
      const float4 a0 = *reinterpret_cast<const float4*>(&A[(size_t)arow * K + k0 + ca]);
      const float4 a1 = *reinterpret_cast<const float4*>(&A[(size_t)arow * K + k0 + ca + 4]);
      a8[0] = a0.x; a8[1] = a0.y; a8[2] = a0.z; a8[3] = a0.w;
      a8[4] = a1.x; a8[5] = a1.y; a8[6] = a1.z; a8[7] = a1.w;
    }
    const float4 b0 = *reinterpret_cast<const float4*>(&B[(size_t)(n0 + rb) * K + k0 + cb]);
    __syncthreads();
#pragma unroll
    for (int q = 0; q < 8; ++q) As[ca + q][ra] = a8[q];
    Bs[cb + 0][rb] = b0.x; Bs[cb + 1][rb] = b0.y;
    Bs[cb + 2][rb] = b0.z; Bs[cb + 3][rb] = b0.w;
    __syncthreads();
#pragma unroll
    for (int kk = 0; kk < 16; ++kk) {
      const float4 av0 = *reinterpret_cast<const float4*>(&As[kk][ty * 8]);
      const float4 av1 = *reinterpret_cast<const float4*>(&As[kk][ty * 8 + 4]);
      const float4 bv  = *reinterpret_cast<const float4*>(&Bs[kk][tx * 4]);
      const float a[8] = {av0.x, av0.y, av0.z, av0.w, av1.x, av1.y, av1.z, av1.w};
      const float bb4[4] = {bv.x, bv.y, bv.z, bv.w};
#pragma unroll
      for (int i = 0; i < 8; ++i)
#pragma unroll
        for (int j = 0; j < 4; ++j) acc[i][j] += a[i] * bb4[j];
    }
  }
  const float4 bias4 = *reinterpret_cast<const float4*>(&bias[n0 + tx * 4]);
  const float bb4[4] = {bias4.x, bias4.y, bias4.z, bias4.w};
#pragma unroll
  for (int i = 0; i < 8; ++i) {
    const size_t cidx = (size_t)(m0 + ty * 8 + i) * N + n0 + tx * 4;
    if constexpr (sizeof(CT) == 2) {
      h2_t lo, hi;
      lo[0] = (_Float16)(acc[i][0] + bb4[0]); lo[1] = (_Float16)(acc[i][1] + bb4[1]);
      hi[0] = (_Float16)(acc[i][2] + bb4[2]); hi[1] = (_Float16)(acc[i][3] + bb4[3]);
      uint2 st;
      st.x = __builtin_bit_cast(unsigned int, lo);
      st.y = __builtin_bit_cast(unsigned int, hi);
      *reinterpret_cast<uint2*>(&C[cidx]) = st;
    } else {
      float4 o;
      o.x = acc[i][0] + bb4[0]; o.y = acc[i][1] + bb4[1];
      o.z = acc[i][2] + bb4[2]; o.w = acc[i][3] + bb4[3];
      *reinterpret_cast<float4*>(&C[cidx]) = o;
    }
  }
}

// ---------------------------------------------------------------------------
// On-chip recurrence, 512 threads per (b,dir). Thread (u = t&255, p = t>>8)
// owns 2 complete gate rows: r0 = p*512+u (gate 2p), r1 = p*512+256+u (2p+1).
// Whh: chunks 0..VC-1 in VGPRs, VC..31 in LDS. h f16 in LDS (broadcast reads).
// Gate pair {ag,ao} handed from p=1 to p=0 via 8B LDS; p=0 holds c/h state.
// xg precomputed f32 (bias included; bwd time-reversed). 2 barriers/step.
// NOTE: single-arg launch_bounds. A 512-thread block already implies
// 2 waves/SIMD (VGPR cap 256); (512,2) made the compiler cap at 128 (r10).
// ---------------------------------------------------------------------------
template <int POOL>
__global__ __launch_bounds__(512) void lstm2(
    const float* __restrict__ xgF, const float* __restrict__ xgB,
    const uint4* __restrict__ whhF, const uint4* __restrict__ whhB,
    _Float16* __restrict__ outp, const int* __restrict__ x_len,
    float* __restrict__ stC, _Float16* __restrict__ stH, float* __restrict__ stP,
    int lenshift, int T, int Twin, int s0) {
  const int b = blockIdx.x;
  const int dir = blockIdx.y;
  const int t_ = threadIdx.x;
  const int u = t_ & 255;
  const int p = t_ >> 8;
  const int len = x_len[b] >> lenshift;
  if (s0 >= len) return;                  // block-uniform
  const int ns = min(Twin, len - s0);
  const int col0 = dir ? 256 : 0;
  const int Tp = T >> 1;
  const int sidx = (b * 2 + dir) * 256 + u;
  const uint4* whh = dir ? whhB : whhF;
  const float* xg = dir ? xgB : xgF;
  const int r0 = p * 512 + u;
  const int r1 = p * 512 + 256 + u;

  // VGPR-resident weight chunks
  uint4 w0[VC], w1[VC];
#pragma unroll
  for (int k = 0; k < VC; ++k) {
    w0[k] = whh[(k << 10) + r0];
    w1[k] = whh[(k << 10) + r1];
  }
  // LDS-resident weight chunks
  __shared__ uint4 wlds[LCH][1024];                // 128 KB
  __shared__ __align__(16) _Float16 hb[2][256];    // 1 KB
  __shared__ float2 gl[256];                       // 2 KB
#pragma unroll
  for (int kc = 0; kc < LCH; ++kc) {
    wlds[kc][r0] = whh[((VC + kc) << 10) + r0];
    wlds[kc][r1] = whh[((VC + kc) << 10) + r1];
  }
  if (t_ < 256) hb[0][t_] = stH[(b * 2 + dir) * 256 + t_];
  float c = 0.f, hpend = 0.f;
  if (p == 0) { c = stC[sidx]; hpend = stP[sidx]; }
  __syncthreads();

  int par = 0;
  const float* xq = xg + (size_t)b * Twin * 1024 + p * 512 + u;
  float xa = xq[0];
  float xb2 = xq[256];
  for (int j = 0; j < ns; ++j) {
    const int s = s0 + j;
    const int t = dir ? (len - 1 - s) : s;
    float a0 = xa, a1 = xb2;
    const uint4* hp = reinterpret_cast<const uint4*>(hb[par]);
#pragma unroll
    for (int k = 0; k < VC; ++k) {
      const uint4 hv = hp[k];
      a0 = dot8(w0[k], hv, a0);
      a1 = dot8(w1[k], hv, a1);
    }
#pragma unroll
    for (int kc = 0; kc < LCH; ++kc) {
      const uint4 hv = hp[VC + kc];
      a0 = dot8(wlds[kc][r0], hv, a0);
      a1 = dot8(wlds[kc][r1], hv, a1);
    }
    if (j + 1 < ns) {   // prefetch next step's xg (independent of h)
      xa = xq[(size_t)(j + 1) * 1024];
      xb2 = xq[(size_t)(j + 1) * 1024 + 256];
    }
    if (p) { gl[u].x = a0; gl[u].y = a1; }
    __syncthreads();  // B1: gate pair {ag,ao} visible
    if (!p) {
      const float2 g2 = gl[u];
      const float gi = sigf(a0);
      const float gf = sigf(a1);
      const float gc = tanhf(g2.x);
      const float go = sigf(g2.y);
      c = gf * c + gi * gc;
      const float h = go * tanhf(c);
      hb[par ^ 1][u] = (_Float16)h;
      if (POOL) {
        if (dir == 0) {
          if (t & 1) outp[((size_t)b * Tp + (t >> 1)) * 512 + col0 + u] = (_Float16)fmaxf(hpend, h);
          else hpend = h;
        } else {
          if (t & 1) hpend = h;
          else outp[((size_t)b * Tp + (t >> 1)) * 512 + col0 + u] = (_Float16)fmaxf(h, hpend);
        }
      } else {
        outp[((size_t)b * T + t) * 512 + col0 + u] = (_Float16)h;
      }
    }
    __syncthreads();  // B2: h complete, gl consumed
    par ^= 1;
  }
  if (p == 0) {
    stH[sidx] = hb[par][u];
    stC[sidx] = c;
    stP[sidx] = hpend;
    if (POOL && dir == 0 && (len & 1) && (len - s0) <= Twin) {
      outp[((size_t)b * Tp + ((len - 1) >> 1)) * 512 + col0 + u] = (_Float16)fmaxf(hpend, 0.f);
    }
  }
}

// r4-style streaming recurrence (fallback for small workspace), ONFLY.
template <int POOL>
__global__ __launch_bounds__(256) void lstm_stream(
    const uint4* __restrict__ xh, int kx8,
    const uint4* __restrict__ wih_f, const uint4* __restrict__ wih_b,
    const float* __restrict__ bias_f, const float* __restrict__ bias_b,
    const uint4* __restrict__ whh_f, const uint4* __restrict__ whh_b,
    _Float16* __restrict__ outp, const int* __restrict__ x_len,
    int lenshift, int T) {
  const int b = blockIdx.x;
  const int dir = blockIdx.y;
  const int u = threadIdx.x;
  const int len = x_len[b] >> lenshift;
  const uint4* wih = dir ? wih_b : wih_f;
  const float* bias = dir ? bias_b : bias_f;
  const uint4* whh0 = (dir ? whh_b : whh_f) + u;
  const int col0 = dir ? 256 : 0;
  const float bi = bias[u], bff = bias[u + 256], bg = bias[u + 512], bo = bias[u + 768];
  __shared__ __align__(16) _Float16 hbuf[2][256];
  hbuf[0][u] = (_Float16)0.f;
  float c = 0.f, hpend = 0.f;
  __syncthreads();
  int cur = 0;
  const int Tp = T >> 1;
  for (int s = 0; s < len; ++s) {
    const int t = dir ? (len - 1 - s) : s;
    float ai = bi, af = bff, ag = bg, ao = bo;
    const uint4* xr = xh + ((size_t)b * T + t) * kx8;
    const uint4* wir = wih + u;
    for (int k8 = 0; k8 < kx8; ++k8) {
      const uint4 xv = xr[k8];
      ai = dot8(wir[0],   xv, ai);
      af = dot8(wir[256], xv, af);
      ag = dot8(wir[512], xv, ag);
      ao = dot8(wir[768], xv, ao);
      wir += 1024;
    }
    const uint4* hp = reinterpret_cast<const uint4*>(hbuf[cur]);
#pragma unroll 4
    for (int k8 = 0; k8 < 32; ++k8) {
      const uint4 hv = hp[k8];
      const uint4* wr = whh0 + (k8 << 10);
      ai = dot8(wr[0],   hv, ai);
      af = dot8(wr[256], hv, af);
      ag = dot8(wr[512], hv, ag);
      ao = dot8(wr[768], hv, ao);
    }
    const float gi = sigf(ai);
    const float gf = sigf(af);
    const float gg = tanhf(ag);
    const float go = sigf(ao);
    c = gf * c + gi * gg;
    const float h = go * tanhf(c);
    if (POOL) {
      if (dir == 0) {
        if (t & 1) outp[((size_t)b * Tp + (t >> 1)) * 512 + col0 + u] = (_Float16)fmaxf(hpend, h);
        else hpend = h;
      } else {
        if (t & 1) hpend = h;
        else outp[((size_t)b * Tp + (t >> 1)) * 512 + col0 + u] = (_Float16)fmaxf(h, hpend);
      }
    } else {
      outp[((size_t)b * T + t) * 512 + col0 + u] = (_Float16)h;
    }
    hbuf[cur ^ 1][u] = (_Float16)h;
    cur ^= 1;
    __syncthreads();
  }
  if (POOL && dir == 0 && (len & 1)) {
    outp[((size_t)b * Tp + ((len - 1) >> 1)) * 512 + col0 + u] = (_Float16)fmaxf(hpend, 0.f);
  }
}

__global__ void lens_k(const int* __restrict__ x_len, float* __restrict__ dst) {
  const int b = threadIdx.x;
  if (b < 32) dst[b] = (float)(x_len[b] >> 1);
}

extern "C" void kernel_launch(void* const* d_in, const int* in_sizes, int n_in,
                              void* d_out, int out_size, void* d_ws, size_t ws_size,
                              hipStream_t stream) {
  (void)in_sizes; (void)n_in; (void)out_size;
  const float* x     = (const float*)d_in[0];
  const int*   x_len = (const int*)d_in[1];
  const float* Wih1f = (const float*)d_in[2];
  const float* Whh1f = (const float*)d_in[3];
  const float* b1f   = (const float*)d_in[4];
  const float* Wih1b = (const float*)d_in[5];
  const float* Whh1b = (const float*)d_in[6];
  const float* b1b   = (const float*)d_in[7];
  const float* Wih2f = (const float*)d_in[8];
  const float* Whh2f = (const float*)d_in[9];
  const float* b2f   = (const float*)d_in[10];
  const float* Wih2b = (const float*)d_in[11];
  const float* Whh2b = (const float*)d_in[12];
  const float* b2b   = (const float*)d_in[13];
  const float* Wlin  = (const float*)d_in[14];
  const float* blin  = (const float*)d_in[15];
  float* outF = (float*)d_out;

  char* w = (char*)d_ws;
  size_t off = 0;
  auto alloc = [&](size_t bytes) -> void* {
    void* p = w + off;
    off += (bytes + 255) & ~(size_t)255;
    return p;
  };
  uint4* wp_hh1f = (uint4*)alloc(524288);
  uint4* wp_hh1b = (uint4*)alloc(524288);
  uint4* wp_hh2f = (uint4*)alloc(524288);
  uint4* wp_hh2b = (uint4*)alloc(524288);
  uint4* wp_ih1f = (uint4*)alloc(163840);      // fallback only
  uint4* wp_ih1b = (uint4*)alloc(163840);
  uint4* wp_ih2f = (uint4*)alloc(1048576);
  uint4* wp_ih2b = (uint4*)alloc(1048576);
  _Float16* pooled = (_Float16*)alloc(32768000);  // [32][1000][512] f16
  _Float16* out2   = (_Float16*)alloc(32768000);  // [32][1000][512] f16 (contiguous)
  float*    stC1 = (float*)alloc(65536);          // states, contiguous block
  _Float16* stH1 = (_Float16*)alloc(32768);
  float*    stP1 = (float*)alloc(65536);
  float*    stC2 = (float*)alloc(65536);
  _Float16* stH2 = (_Float16*)alloc(32768);
  float*    stP2 = (float*)alloc(65536);
  const size_t var_off = off;
  float* varrF = (float*)(w + var_off);
  float* xgwF = varrF;                   // [32][500][1024] f32 = 65,536,000 B
  float* xgwB = varrF + 16384000;        // second 65,536,000 B (131MB total)
  _Float16* x_h = (_Float16*)(w + var_off);  // fallback: [32][2000][80] f16

  const int main_tier = (ws_size >= var_off + 131072000ULL) ? 1 : 0;

  // Whh packs (always)
  pack_w<<<128, 256, 0, stream>>>(Whh1f, wp_hh1f, 256);
  pack_w<<<128, 256, 0, stream>>>(Whh1b, wp_hh1b, 256);
  pack_w<<<128, 256, 0, stream>>>(Whh2f, wp_hh2f, 256);
  pack_w<<<128, 256, 0, stream>>>(Whh2b, wp_hh2b, 256);
  // zero pooled+out2 (contiguous) and all state buffers (contiguous)
  zero16<<<16000, 256, 0, stream>>>((uint4*)pooled, 4096000);
  zero16<<<80, 256, 0, stream>>>((uint4*)stC1, 20480);

  if (main_tier) {
    // ---- Layer 1: 4 windows of 500 steps, f32 xg ----
    for (int w4 = 0; w4 < 4; ++w4) {
      const int t0 = 500 * w4;
      gemm_any<float, float><<<dim3(16, 125), 256, 0, stream>>>(
          x, Wih1f, b1f, xgwF, 16000, 1024, 80, 500, 2000, t0, 0, x_len, 0);
      gemm_any<float, float><<<dim3(16, 125), 256, 0, stream>>>(
          x, Wih1b, b1b, xgwB, 16000, 1024, 80, 500, 2000, t0, 1, x_len, 0);
      lstm2<1><<<dim3(32, 2), 512, 0, stream>>>(
          xgwF, xgwB, wp_hh1f, wp_hh1b, pooled, x_len,
          stC1, stH1, stP1, 0, 2000, 500, t0);
    }
    // ---- Layer 2: 2 windows of 500 steps (same 131MB region) ----
    for (int w2 = 0; w2 < 2; ++w2) {
      const int t0 = 500 * w2;
      gemm_any<_Float16, float><<<dim3(16, 125), 256, 0, stream>>>(
          pooled, Wih2f, b2f, xgwF, 16000, 1024, 512, 500, 1000, t0, 0, x_len, 1);
      gemm_any<_Float16, float><<<dim3(16, 125), 256, 0, stream>>>(
          pooled, Wih2b, b2b, xgwB, 16000, 1024, 512, 500, 1000, t0, 1, x_len, 1);
      lstm2<0><<<dim3(32, 2), 512, 0, stream>>>(
          xgwF, xgwB, wp_hh2f, wp_hh2b, out2, x_len,
          stC2, stH2, stP2, 1, 1000, 500, t0);
    }
  } else {
    // ---- Fallback (r4-proven): ONFLY streaming both layers ----
    pack_w<<<40, 256, 0, stream>>>(Wih1f, wp_ih1f, 80);
    pack_w<<<40, 256, 0, stream>>>(Wih1b, wp_ih1b, 80);
    pack_w<<<256, 256, 0, stream>>>(Wih2f, wp_ih2f, 512);
    pack_w<<<256, 256, 0, stream>>>(Wih2b, wp_ih2b, 512);
    pack_flat<<<20000, 256, 0, stream>>>(x, x_h, 5120000);
    lstm_stream<1><<<dim3(32, 2), 256, 0, stream>>>(
        (const uint4*)x_h, 10, wp_ih1f, wp_ih1b, b1f, b1b,
        wp_hh1f, wp_hh1b, pooled, x_len, 0, 2000);
    lstm_stream<0><<<dim3(32, 2), 256, 0, stream>>>(
        (const uint4*)pooled, 64, wp_ih2f, wp_ih2b, b2f, b2b,
        wp_hh2f, wp_hh2b, out2, x_len, 1, 1000);
  }

  // ---- Final linear + lens ----
  gemm_any<_Float16, float><<<dim3(8, 250), 256, 0, stream>>>(
      out2, Wlin, blin, outF, 32000, 512, 512, 0, 0, 0, 0, nullptr, 0);
  lens_k<<<1, 32, 0, stream>>>(x_len, outF + (size_t)16384000);
}

// Round 12
// 30606.897 us; speedup vs baseline: 1.0026x; 1.0014x over previous
//
#include <hip/hip_runtime.h>

// ---------------------------------------------------------------------------
// StackedBLSTMEmbedding: B=32, T=2000, D=80, H=256/dir, HD=512, O=512
// Round 12: ONE change vs r11: __launch_bounds__(512, 1) on lstm2.
//   Solved r10/r11 mystery: HIP's 2nd launch_bounds arg is min BLOCKS/CU.
//   (512,2)=16 waves/CU -> 128-reg cap (observed); default (512) also 128.
//   (512,1)=8 waves/CU = 2 waves/SIMD -> 256-reg cap: the 192-reg weight
//   array stays resident. Verified against r7 (256,1)->244 regs.
//   lstm2: thread owns 2 full gate rows, Whh 24 chunks VGPR + 8 chunks LDS,
//   precise expf/tanhf, f32 xg in 500-step windows both layers.
// ---------------------------------------------------------------------------

typedef _Float16 h2_t __attribute__((ext_vector_type(2)));

constexpr int VC = 24;            // Whh k8-chunks in VGPRs (48 uint4 = 192 regs)
constexpr int LCH = 32 - VC;      // 8 chunks in LDS (128 KB)

__device__ __forceinline__ float dot2acc(unsigned int w, unsigned int h, float acc) {
  h2_t wv = __builtin_bit_cast(h2_t, w);
  h2_t hv = __builtin_bit_cast(h2_t, h);
#if __has_builtin(__builtin_amdgcn_fdot2)
  return __builtin_amdgcn_fdot2(wv, hv, acc, false);
#else
  return acc + (float)wv[0] * (float)hv[0] + (float)wv[1] * (float)hv[1];
#endif
}

__device__ __forceinline__ float dot8(uint4 w, uint4 h, float acc) {
  acc = dot2acc(w.x, h.x, acc);
  acc = dot2acc(w.y, h.y, acc);
  acc = dot2acc(w.z, h.z, acc);
  acc = dot2acc(w.w, h.w, acc);
  return acc;
}

__device__ __forceinline__ float sigf(float x) { return 1.f / (1.f + expf(-x)); }

// Pack fp32 W[1024][K] -> f16 uint4 Wp[k8][1024] (k8 = k/8).
__global__ __launch_bounds__(256) void pack_w(const float* __restrict__ W,
                                              uint4* __restrict__ Wp, int K) {
  const int idx = blockIdx.x * 256 + threadIdx.x;
  const int total = (K >> 3) << 10;
  if (idx >= total) return;
  const int g = idx & 1023;
  const int k8 = idx >> 10;
  const float* src = W + (size_t)g * K + k8 * 8;
  h2_t p0, p1, p2, p3;
  p0[0] = (_Float16)src[0]; p0[1] = (_Float16)src[1];
  p1[0] = (_Float16)src[2]; p1[1] = (_Float16)src[3];
  p2[0] = (_Float16)src[4]; p2[1] = (_Float16)src[5];
  p3[0] = (_Float16)src[6]; p3[1] = (_Float16)src[7];
  uint4 o;
  o.x = __builtin_bit_cast(unsigned int, p0);
  o.y = __builtin_bit_cast(unsigned int, p1);
  o.z = __builtin_bit_cast(unsigned int, p2);
  o.w = __builtin_bit_cast(unsigned int, p3);
  Wp[(size_t)k8 * 1024 + g] = o;
}

__global__ __launch_bounds__(256) void pack_flat(const float* __restrict__ src,
                                                 _Float16* __restrict__ dst, int n) {
  const int i = blockIdx.x * 256 + threadIdx.x;
  if (i < n) dst[i] = (_Float16)src[i];
}

__global__ __launch_bounds__(256) void zero16(uint4* __restrict__ p, int n16) {
  const int i = blockIdx.x * 256 + threadIdx.x;
  if (i < n16) { uint4 z; z.x = z.y = z.z = z.w = 0u; p[i] = z; }
}

// C[M][N] = A'[M][K] @ B[N][K]^T + bias.  M%128==0, N%64==0, K%16==0.
// Window remap (Twin>0): row m -> b=m/Twin, ti=t0+m%Twin; REV: ti=len_b-1-ti
// (clamped); A-row = b*Tfull+ti. Twin==0: identity.
template <typename AT, typename CT>
__global__ __launch_bounds__(256) void gemm_any(
    const AT* __restrict__ A, const float* __restrict__ B,
    const float* __restrict__ bias, CT* __restrict__ C,
    int M, int N, int K, int Twin, int Tfull, int t0, int REV,
    const int* __restrict__ x_len, int lensh) {
  __shared__ float As[16][128];
  __shared__ float Bs[16][64];
  const int tid = threadIdx.x;
  const int m0 = blockIdx.y * 128, n0 = blockIdx.x * 64;
  const int ra = tid >> 1;
  const int ca = (tid & 1) * 8;
  const int rb = tid >> 2;
  const int cb = (tid & 3) * 4;
  const int ty = tid >> 4;
  const int tx = tid & 15;
  const int am = m0 + ra;
  int arow = am;
  if (Twin > 0) {
    const int bb = am / Twin;
    int ti = t0 + (am - bb * Twin);
    if (REV) {
      const int L = x_len[bb] >> lensh;
      ti = L - 1 - ti;
      ti = ti < 0 ? 0 : ti;
    }
    arow = bb * Tfull + ti;
  }
  float acc[8][4] = {};
  for (int k0 = 0; k0 < K; k0 += 16) {
    float a8[8];
    if constexpr (sizeof(AT) == 2) {
      const uint4 av = *reinterpret_cast<const uint4*>(&A[(size_t)arow * K + k0 + ca]);
      h2_t p0 = __builtin_bit_cast(h2_t, av.x);
      h2_t p1 = __builtin_bit_cast(h2_t, av.y);
      h2_t p2 = __builtin_bit_cast(h2_t, av.z);
      h2_t p3 = __builtin_bit_cast(h2_t, av.w);
      a8[0] = (float)p0[0]; a8[1] = (float)p0[1];
      a8[2] = (float)p1[0]; a8[3] = (float)p1[1];
      a8[4] = (float)p2[0]; a8[5] = (float)p2[1];
      a8[6] = (float)p3[0]; a8[7] = (float)p3[1];
    } else {
      const float4 a0 = *reinterpret_cast<const float4*>(&A[(size_t)arow * K + k0 + ca]);
      const float4 a1 = *reinterpret_cast<const float4*>(&A[(size_t)arow * K + k0 + ca + 4]);
      a8[0] = a0.x; a8[1] = a0.y; a8[2] = a0.z; a8[3] = a0.w;
      a8[4] = a1.x; a8[5] = a1.y; a8[6] = a1.z; a8[7] = a1.w;
    }
    const float4 b0 = *reinterpret_cast<const float4*>(&B[(size_t)(n0 + rb) * K + k0 + cb]);
    __syncthreads();
#pragma unroll
    for (int q = 0; q < 8; ++q) As[ca + q][ra] = a8[q];
    Bs[cb + 0][rb] = b0.x; Bs[cb + 1][rb] = b0.y;
    Bs[cb + 2][rb] = b0.z; Bs[cb + 3][rb] = b0.w;
    __syncthreads();
#pragma unroll
    for (int kk = 0; kk < 16; ++kk) {
      const float4 av0 = *reinterpret_cast<const float4*>(&As[kk][ty * 8]);
      const float4 av1 = *reinterpret_cast<const float4*>(&As[kk][ty * 8 + 4]);
      const float4 bv  = *reinterpret_cast<const float4*>(&Bs[kk][tx * 4]);
      const float a[8] = {av0.x, av0.y, av0.z, av0.w, av1.x, av1.y, av1.z, av1.w};
      const float bb4[4] = {bv.x, bv.y, bv.z, bv.w};
#pragma unroll
      for (int i = 0; i < 8; ++i)
#pragma unroll
        for (int j = 0; j < 4; ++j) acc[i][j] += a[i] * bb4[j];
    }
  }
  const float4 bias4 = *reinterpret_cast<const float4*>(&bias[n0 + tx * 4]);
  const float bb4[4] = {bias4.x, bias4.y, bias4.z, bias4.w};
#pragma unroll
  for (int i = 0; i < 8; ++i) {
    const size_t cidx = (size_t)(m0 + ty * 8 + i) * N + n0 + tx * 4;
    if constexpr (sizeof(CT) == 2) {
      h2_t lo, hi;
      lo[0] = (_Float16)(acc[i][0] + bb4[0]); lo[1] = (_Float16)(acc[i][1] + bb4[1]);
      hi[0] = (_Float16)(acc[i][2] + bb4[2]); hi[1] = (_Float16)(acc[i][3] + bb4[3]);
      uint2 st;
      st.x = __builtin_bit_cast(unsigned int, lo);
      st.y = __builtin_bit_cast(unsigned int, hi);
      *reinterpret_cast<uint2*>(&C[cidx]) = st;
    } else {
      float4 o;
      o.x = acc[i][0] + bb4[0]; o.y = acc[i][1] + bb4[1];
      o.z = acc[i][2] + bb4[2]; o.w = acc[i][3] + bb4[3];
      *reinterpret_cast<float4*>(&C[cidx]) = o;
    }
  }
}

// ---------------------------------------------------------------------------
// On-chip recurrence, 512 threads per (b,dir). Thread (u = t&255, p = t>>8)
// owns 2 complete gate rows: r0 = p*512+u (gate 2p), r1 = p*512+256+u (2p+1).
// Whh: chunks 0..VC-1 in VGPRs, VC..31 in LDS. h f16 in LDS (broadcast reads).
// Gate pair {ag,ao} handed from p=1 to p=0 via 8B LDS; p=0 holds c/h state.
// xg precomputed f32 (bias included; bwd time-reversed). 2 barriers/step.
// __launch_bounds__(512, 1): 2nd arg is min BLOCKS/CU (HIP semantics) --
// 1 block x 8 waves = 2 waves/SIMD -> 256-VGPR cap. (512,2) or default
// target 4 waves/SIMD -> 128-reg cap -> weight spill (r10/r11 measured).
// ---------------------------------------------------------------------------
template <int POOL>
__global__ __launch_bounds__(512, 1) void lstm2(
    const float* __restrict__ xgF, const float* __restrict__ xgB,
    const uint4* __restrict__ whhF, const uint4* __restrict__ whhB,
    _Float16* __restrict__ outp, const int* __restrict__ x_len,
    float* __restrict__ stC, _Float16* __restrict__ stH, float* __restrict__ stP,
    int lenshift, int T, int Twin, int s0) {
  const int b = blockIdx.x;
  const int dir = blockIdx.y;
  const int t_ = threadIdx.x;
  const int u = t_ & 255;
  const int p = t_ >> 8;
  const int len = x_len[b] >> lenshift;
  if (s0 >= len) return;                  // block-uniform
  const int ns = min(Twin, len - s0);
  const int col0 = dir ? 256 : 0;
  const int Tp = T >> 1;
  const int sidx = (b * 2 + dir) * 256 + u;
  const uint4* whh = dir ? whhB : whhF;
  const float* xg = dir ? xgB : xgF;
  const int r0 = p * 512 + u;
  const int r1 = p * 512 + 256 + u;

  // VGPR-resident weight chunks
  uint4 w0[VC], w1[VC];
#pragma unroll
  for (int k = 0; k < VC; ++k) {
    w0[k] = whh[(k << 10) + r0];
    w1[k] = whh[(k << 10) + r1];
  }
  // LDS-resident weight chunks
  __shared__ uint4 wlds[LCH][1024];                // 128 KB
  __shared__ __align__(16) _Float16 hb[2][256];    // 1 KB
  __shared__ float2 gl[256];                       // 2 KB
#pragma unroll
  for (int kc = 0; kc < LCH; ++kc) {
    wlds[kc][r0] = whh[((VC + kc) << 10) + r0];
    wlds[kc][r1] = whh[((VC + kc) << 10) + r1];
  }
  if (t_ < 256) hb[0][t_] = stH[(b * 2 + dir) * 256 + t_];
  float c = 0.f, hpend = 0.f;
  if (p == 0) { c = stC[sidx]; hpend = stP[sidx]; }
  __syncthreads();

  int par = 0;
  const float* xq = xg + (size_t)b * Twin * 1024 + p * 512 + u;
  float xa = xq[0];
  float xb2 = xq[256];
  for (int j = 0; j < ns; ++j) {
    const int s = s0 + j;
    const int t = dir ? (len - 1 - s) : s;
    float a0 = xa, a1 = xb2;
    const uint4* hp = reinterpret_cast<const uint4*>(hb[par]);
#pragma unroll
    for (int k = 0; k < VC; ++k) {
      const uint4 hv = hp[k];
      a0 = dot8(w0[k], hv, a0);
      a1 = dot8(w1[k], hv, a1);
    }
#pragma unroll
    for (int kc = 0; kc < LCH; ++kc) {
      const uint4 hv = hp[VC + kc];
      a0 = dot8(wlds[kc][r0], hv, a0);
      a1 = dot8(wlds[kc][r1], hv, a1);
    }
    if (j + 1 < ns) {   // prefetch next step's xg (independent of h)
      xa = xq[(size_t)(j + 1) * 1024];
      xb2 = xq[(size_t)(j + 1) * 1024 + 256];
    }
    if (p) { gl[u].x = a0; gl[u].y = a1; }
    __syncthreads();  // B1: gate pair {ag,ao} visible
    if (!p) {
      const float2 g2 = gl[u];
      const float gi = sigf(a0);
      const float gf = sigf(a1);
      const float gc = tanhf(g2.x);
      const float go = sigf(g2.y);
      c = gf * c + gi * gc;
      const float h = go * tanhf(c);
      hb[par ^ 1][u] = (_Float16)h;
      if (POOL) {
        if (dir == 0) {
          if (t & 1) outp[((size_t)b * Tp + (t >> 1)) * 512 + col0 + u] = (_Float16)fmaxf(hpend, h);
          else hpend = h;
        } else {
          if (t & 1) hpend = h;
          else outp[((size_t)b * Tp + (t >> 1)) * 512 + col0 + u] = (_Float16)fmaxf(h, hpend);
        }
      } else {
        outp[((size_t)b * T + t) * 512 + col0 + u] = (_Float16)h;
      }
    }
    __syncthreads();  // B2: h complete, gl consumed
    par ^= 1;
  }
  if (p == 0) {
    stH[sidx] = hb[par][u];
    stC[sidx] = c;
    stP[sidx] = hpend;
    if (POOL && dir == 0 && (len & 1) && (len - s0) <= Twin) {
      outp[((size_t)b * Tp + ((len - 1) >> 1)) * 512 + col0 + u] = (_Float16)fmaxf(hpend, 0.f);
    }
  }
}

// r4-style streaming recurrence (fallback for small workspace), ONFLY.
template <int POOL>
__global__ __launch_bounds__(256) void lstm_stream(
    const uint4* __restrict__ xh, int kx8,
    const uint4* __restrict__ wih_f, const uint4* __restrict__ wih_b,
    const float* __restrict__ bias_f, const float* __restrict__ bias_b,
    const uint4* __restrict__ whh_f, const uint4* __restrict__ whh_b,
    _Float16* __restrict__ outp, const int* __restrict__ x_len,
    int lenshift, int T) {
  const int b = blockIdx.x;
  const int dir = blockIdx.y;
  const int u = threadIdx.x;
  const int len = x_len[b] >> lenshift;
  const uint4* wih = dir ? wih_b : wih_f;
  const float* bias = dir ? bias_b : bias_f;
  const uint4* whh0 = (dir ? whh_b : whh_f) + u;
  const int col0 = dir ? 256 : 0;
  const float bi = bias[u], bff = bias[u + 256], bg = bias[u + 512], bo = bias[u + 768];
  __shared__ __align__(16) _Float16 hbuf[2][256];
  hbuf[0][u] = (_Float16)0.f;
  float c = 0.f, hpend = 0.f;
  __syncthreads();
  int cur = 0;
  const int Tp = T >> 1;
  for (int s = 0; s < len; ++s) {
    const int t = dir ? (len - 1 - s) : s;
    float ai = bi, af = bff, ag = bg, ao = bo;
    const uint4* xr = xh + ((size_t)b * T + t) * kx8;
    const uint4* wir = wih + u;
    for (int k8 = 0; k8 < kx8; ++k8) {
      const uint4 xv = xr[k8];
      ai = dot8(wir[0],   xv, ai);
      af = dot8(wir[256], xv, af);
      ag = dot8(wir[512], xv, ag);
      ao = dot8(wir[768], xv, ao);
      wir += 1024;
    }
    const uint4* hp = reinterpret_cast<const uint4*>(hbuf[cur]);
#pragma unroll 4
    for (int k8 = 0; k8 < 32; ++k8) {
      const uint4 hv = hp[k8];
      const uint4* wr = whh0 + (k8 << 10);
      ai = dot8(wr[0],   hv, ai);
      af = dot8(wr[256], hv, af);
      ag = dot8(wr[512], hv, ag);
      ao = dot8(wr[768], hv, ao);
    }
    const float gi = sigf(ai);
    const float gf = sigf(af);
    const float gg = tanhf(ag);
    const float go = sigf(ao);
    c = gf * c + gi * gg;
    const float h = go * tanhf(c);
    if (POOL) {
      if (dir == 0) {
        if (t & 1) outp[((size_t)b * Tp + (t >> 1)) * 512 + col0 + u] = (_Float16)fmaxf(hpend, h);
        else hpend = h;
      } else {
        if (t & 1) hpend = h;
        else outp[((size_t)b * Tp + (t >> 1)) * 512 + col0 + u] = (_Float16)fmaxf(h, hpend);
      }
    } else {
      outp[((size_t)b * T + t) * 512 + col0 + u] = (_Float16)h;
    }
    hbuf[cur ^ 1][u] = (_Float16)h;
    cur ^= 1;
    __syncthreads();
  }
  if (POOL && dir == 0 && (len & 1)) {
    outp[((size_t)b * Tp + ((len - 1) >> 1)) * 512 + col0 + u] = (_Float16)fmaxf(hpend, 0.f);
  }
}

__global__ void lens_k(const int* __restrict__ x_len, float* __restrict__ dst) {
  const int b = threadIdx.x;
  if (b < 32) dst[b] = (float)(x_len[b] >> 1);
}

extern "C" void kernel_launch(void* const* d_in, const int* in_sizes, int n_in,
                              void* d_out, int out_size, void* d_ws, size_t ws_size,
                              hipStream_t stream) {
  (void)in_sizes; (void)n_in; (void)out_size;
  const float* x     = (const float*)d_in[0];
  const int*   x_len = (const int*)d_in[1];
  const float* Wih1f = (const float*)d_in[2];
  const float* Whh1f = (const float*)d_in[3];
  const float* b1f   = (const float*)d_in[4];
  const float* Wih1b = (const float*)d_in[5];
  const float* Whh1b = (const float*)d_in[6];
  const float* b1b   = (const float*)d_in[7];
  const float* Wih2f = (const float*)d_in[8];
  const float* Whh2f = (const float*)d_in[9];
  const float* b2f   = (const float*)d_in[10];
  const float* Wih2b = (const float*)d_in[11];
  const float* Whh2b = (const float*)d_in[12];
  const float* b2b   = (const float*)d_in[13];
  const float* Wlin  = (const float*)d_in[14];
  const float* blin  = (const float*)d_in[15];
  float* outF = (float*)d_out;

  char* w = (char*)d_ws;
  size_t off = 0;
  auto alloc = [&](size_t bytes) -> void* {
    void* p = w + off;
    off += (bytes + 255) & ~(size_t)255;
    return p;
  };
  uint4* wp_hh1f = (uint4*)alloc(524288);
  uint4* wp_hh1b = (uint4*)alloc(524288);
  uint4* wp_hh2f = (uint4*)alloc(524288);
  uint4* wp_hh2b = (uint4*)alloc(524288);
  uint4* wp_ih1f = (uint4*)alloc(163840);      // fallback only
  uint4* wp_ih1b = (uint4*)alloc(163840);
  uint4* wp_ih2f = (uint4*)alloc(1048576);
  uint4* wp_ih2b = (uint4*)alloc(1048576);
  _Float16* pooled = (_Float16*)alloc(32768000);  // [32][1000][512] f16
  _Float16* out2   = (_Float16*)alloc(32768000);  // [32][1000][512] f16 (contiguous)
  float*    stC1 = (float*)alloc(65536);          // states, contiguous block
  _Float16* stH1 = (_Float16*)alloc(32768);
  float*    stP1 = (float*)alloc(65536);
  float*    stC2 = (float*)alloc(65536);
  _Float16* stH2 = (_Float16*)alloc(32768);
  float*    stP2 = (float*)alloc(65536);
  const size_t var_off = off;
  float* varrF = (float*)(w + var_off);
  float* xgwF = varrF;                   // [32][500][1024] f32 = 65,536,000 B
  float* xgwB = varrF + 16384000;        // second 65,536,000 B (131MB total)
  _Float16* x_h = (_Float16*)(w + var_off);  // fallback: [32][2000][80] f16

  const int main_tier = (ws_size >= var_off + 131072000ULL) ? 1 : 0;

  // Whh packs (always)
  pack_w<<<128, 256, 0, stream>>>(Whh1f, wp_hh1f, 256);
  pack_w<<<128, 256, 0, stream>>>(Whh1b, wp_hh1b, 256);
  pack_w<<<128, 256, 0, stream>>>(Whh2f, wp_hh2f, 256);
  pack_w<<<128, 256, 0, stream>>>(Whh2b, wp_hh2b, 256);
  // zero pooled+out2 (contiguous) and all state buffers (contiguous)
  zero16<<<16000, 256, 0, stream>>>((uint4*)pooled, 4096000);
  zero16<<<80, 256, 0, stream>>>((uint4*)stC1, 20480);

  if (main_tier) {
    // ---- Layer 1: 4 windows of 500 steps, f32 xg ----
    for (int w4 = 0; w4 < 4; ++w4) {
      const int t0 = 500 * w4;
      gemm_any<float, float><<<dim3(16, 125), 256, 0, stream>>>(
          x, Wih1f, b1f, xgwF, 16000, 1024, 80, 500, 2000, t0, 0, x_len, 0);
      gemm_any<float, float><<<dim3(16, 125), 256, 0, stream>>>(
          x, Wih1b, b1b, xgwB, 16000, 1024, 80, 500, 2000, t0, 1, x_len, 0);
      lstm2<1><<<dim3(32, 2), 512, 0, stream>>>(
          xgwF, xgwB, wp_hh1f, wp_hh1b, pooled, x_len,
          stC1, stH1, stP1, 0, 2000, 500, t0);
    }
    // ---- Layer 2: 2 windows of 500 steps (same 131MB region) ----
    for (int w2 = 0; w2 < 2; ++w2) {
      const int t0 = 500 * w2;
      gemm_any<_Float16, float><<<dim3(16, 125), 256, 0, stream>>>(
          pooled, Wih2f, b2f, xgwF, 16000, 1024, 512, 500, 1000, t0, 0, x_len, 1);
      gemm_any<_Float16, float><<<dim3(16, 125), 256, 0, stream>>>(
          pooled, Wih2b, b2b, xgwB, 16000, 1024, 512, 500, 1000, t0, 1, x_len, 1);
      lstm2<0><<<dim3(32, 2), 512, 0, stream>>>(
          xgwF, xgwB, wp_hh2f, wp_hh2b, out2, x_len,
          stC2, stH2, stP2, 1, 1000, 500, t0);
    }
  } else {
    // ---- Fallback (r4-proven): ONFLY streaming both layers ----
    pack_w<<<40, 256, 0, stream>>>(Wih1f, wp_ih1f, 80);
    pack_w<<<40, 256, 0, stream>>>(Wih1b, wp_ih1b, 80);
    pack_w<<<256, 256, 0, stream>>>(Wih2f, wp_ih2f, 512);
    pack_w<<<256, 256, 0, stream>>>(Wih2b, wp_ih2b, 512);
    pack_flat<<<20000, 256, 0, stream>>>(x, x_h, 5120000);
    lstm_stream<1><<<dim3(32, 2), 256, 0, stream>>>(
        (const uint4*)x_h, 10, wp_ih1f, wp_ih1b, b1f, b1b,
        wp_hh1f, wp_hh1b, pooled, x_len, 0, 2000);
    lstm_stream<0><<<dim3(32, 2), 256, 0, stream>>>(
        (const uint4*)pooled, 64, wp_ih2f, wp_ih2b, b2f, b2b,
        wp_hh2f, wp_hh2b, out2, x_len, 1, 1000);
  }

  // ---- Final linear + lens ----
  gemm_any<_Float16, float><<<dim3(8, 250), 256, 0, stream>>>(
      out2, Wlin, blin, outF, 32000, 512, 512, 0, 0, 0, 0, nullptr, 0);
  lens_k<<<1, 32, 0, stream>>>(x_len, outF + (size_t)16384000);
}